// Round 13
// baseline (104.811 us; speedup 1.0000x reference)
//
#include <hip/hip_runtime.h>
#include <hip/hip_fp16.h>
#include <math.h>

typedef _Float16 f16x8 __attribute__((ext_vector_type(8)));
typedef _Float16 f16x4 __attribute__((ext_vector_type(4)));
typedef float f32x4 __attribute__((ext_vector_type(4)));
typedef float f32x16 __attribute__((ext_vector_type(16)));

#define DD     128     // d
#define D2     256     // 2d
#define NB     8192    // batch
#define NCLS   5
#define KSPLIT 8
#define BM     128
#define PPAD   258     // row stride 516B = 129 dw == 1 mod 32 -> conflict-free
#define NSB    36      // 8x8 block-triangle: 28 off-diag (V+V^T) + 8 diag (raw V)
#define SB_BYTES  262144u              // 128 granules * 128 n * 16 B
#define TAIL_OFF  (36u * 262144u)      // W_w tail after all superblocks
#define PART_OFF  (10u * 1048576u)     // fp32 partials at +10 MB

// ---- prep: build symmetrized Vt fp16 in granule layout [kb][n][8] (unchanged) -----------
__global__ void prep_vt(const float* __restrict__ V, const float* __restrict__ Ww,
                        _Float16* __restrict__ Vt) {
    int t = blockIdx.x * 256 + threadIdx.x;      // thread per (granule-unit, n)
    int u = t >> 7;
    int n = t & 127;
    f16x8 v;
    if (u < NSB * 128) {
        int s = u >> 7, g = u & 127;
        int bi = 0, rem = s;
        while (rem >= 8 - bi) { rem -= 8 - bi; ++bi; }
        int bj = bi + rem;
        int i  = bi * 32 + (g >> 2);
        int j0 = bj * 32 + (g & 3) * 8;
        if (bi == bj) {
            #pragma unroll
            for (int e = 0; e < 8; ++e)
                v[e] = (_Float16)V[((size_t)i * 256 + j0 + e) * 128 + n];
        } else {
            #pragma unroll
            for (int e = 0; e < 8; ++e)
                v[e] = (_Float16)(V[((size_t)i * 256 + j0 + e) * 128 + n]
                                + V[((size_t)(j0 + e) * 256 + i) * 128 + n]);
        }
    } else {
        int g = u - NSB * 128;                   // 0..31
        int j0 = g * 8;
        #pragma unroll
        for (int e = 0; e < 8; ++e)
            v[e] = (_Float16)Ww[n * D2 + j0 + e];
    }
    *(f16x8*)(Vt + (size_t)u * 1024 + n * 8) = v;
}

// ---------------- main: 32x32x16 MFMA version -------------------------------------------
// 2x2 wave grid, wave tile 64x64 = 2x2 of 32x32. 8 MFMA/cluster (was 16), same FLOPs.
// A frag: row=lane&31, k=8*(lane>>5)+e.  B frag: col=lane&31, k=8*(lane>>5)+e.
// C/D:   col=lane&31, row=(r&3)+8*(r>>2)+4*(lane>>5)  [m74/m101]
__global__ __launch_bounds__(256, 2) void gemm_bilinear(
        const float* __restrict__ left, const float* __restrict__ right,
        const _Float16* __restrict__ Vt, float* __restrict__ part) {
    __shared__ _Float16 P[BM][PPAD];

    const int bid = blockIdx.x;
    const int ks  = bid & 7;       // == XCD id under round-robin dispatch -> slice per XCD L2
    const int m0  = (bid >> 3) * BM;
    const int tid = threadIdx.x;

    // stage phrase tile (fp32 global -> fp16 LDS), coalesced float4 reads
    for (int it = 0; it < 32; ++it) {
        int f4  = it * 256 + tid;          // float4 index over [128][256]
        int row = f4 >> 6;
        int col = (f4 & 63) * 4;
        const float* src = (col < DD) ? (left  + (size_t)(m0 + row) * DD + col)
                                      : (right + (size_t)(m0 + row) * DD + (col - DD));
        float4 x = *(const float4*)src;
        f16x4 hv;
        hv[0] = (_Float16)x.x; hv[1] = (_Float16)x.y;
        hv[2] = (_Float16)x.z; hv[3] = (_Float16)x.w;
        *(f16x4*)&P[row][col] = hv;
    }
    __syncthreads();

    const int lane = tid & 63;
    const int wid  = tid >> 6;
    const int wm   = wid >> 1, wn = wid & 1;   // 2x2 wave grid, 64x64 wave tile
    const int l31  = lane & 31;
    const int lg2  = lane >> 5;                // 0..1 -> k-subgroup
    const int rowb = wm * 64;
    const int coln = wn * 64;

    f32x16 acc[2][2];
    #pragma unroll
    for (int u = 0; u < 2; ++u)
        #pragma unroll
        for (int w = 0; w < 2; ++w)
            acc[u][w] = (f32x16){0.f,0.f,0.f,0.f,0.f,0.f,0.f,0.f,
                                 0.f,0.f,0.f,0.f,0.f,0.f,0.f,0.f};

    // lane byte base into Vt: kb += lg2 (k-subgroup), n = coln + l31
    const unsigned lane_byte = (unsigned)(lg2 * 2048 + (coln + l31) * 16);
    #define LDV(off) (*(const f16x8*)((const char*)Vt + (off)))

    // BUF[0]=(k0,n0) BUF[1]=(k0,n1) BUF[2]=(k1,n0) BUF[3]=(k1,n1)
    // k1 = kb+2 granules = +4096 B; n1 = +32 cols = +512 B
    #define LOADB(BUF)                                                                    \
        asm volatile("global_load_dwordx4 %0, %4, %6\n\t"                                 \
                     "global_load_dwordx4 %1, %4, %6 offset:512\n\t"                      \
                     "global_load_dwordx4 %2, %5, %6\n\t"                                 \
                     "global_load_dwordx4 %3, %5, %6 offset:512"                          \
            : "=&v"(BUF[0]), "=&v"(BUF[1]), "=&v"(BUF[2]), "=&v"(BUF[3])                  \
            : "v"(voffA), "v"(voffB), "s"(Vt));                                           \
        voffA += 8192u; voffB += 8192u;

    #define WAITN(N)                                                                      \
        asm volatile("s_waitcnt vmcnt(" #N ")");                                          \
        __builtin_amdgcn_sched_barrier(0);

    #define MFMA_CLUSTER(BUF, IBE)                                                        \
        __builtin_amdgcn_s_setprio(1);                                                    \
        _Pragma("unroll")                                                                 \
        for (int mr = 0; mr < 2; ++mr) {                                                  \
            const _Float16 sc = pis[mr][IBE];                                             \
            const f16x8 a0 = pj2[mr][0] * sc;                                             \
            const f16x8 a1 = pj2[mr][1] * sc;                                             \
            acc[mr][0] = __builtin_amdgcn_mfma_f32_32x32x16_f16(a0, BUF[0], acc[mr][0], 0, 0, 0); \
            acc[mr][1] = __builtin_amdgcn_mfma_f32_32x32x16_f16(a0, BUF[1], acc[mr][1], 0, 0, 0); \
            acc[mr][0] = __builtin_amdgcn_mfma_f32_32x32x16_f16(a1, BUF[2], acc[mr][0], 0, 0, 0); \
            acc[mr][1] = __builtin_amdgcn_mfma_f32_32x32x16_f16(a1, BUF[3], acc[mr][1], 0, 0, 0); \
        }                                                                                 \
        __builtin_amdgcn_s_setprio(0);

    #define LOAD_PIS(IBC)                                                                 \
        f16x8 pis[2];                                                                     \
        _Pragma("unroll")                                                                 \
        for (int mr = 0; mr < 2; ++mr)                                                    \
            pis[mr] = *(const f16x8*)&P[rowb + mr * 32 + l31][bi * 32 + (IBC) * 8];

    #pragma unroll 1
    for (int si = 0; si < 5; ++si) {
        int s, ibcS, ibcE;
        if (si < 4) { s = ks * 4 + si;      ibcS = 0;            ibcE = 4; }
        else        { s = 32 + (ks >> 1);   ibcS = (ks & 1) * 2; ibcE = ibcS + 2; }

        // decode (bi, bj) from triangle slot (wave-uniform scalar loop)
        int bi = 0, rem = s;
        while (rem >= 8 - bi) { rem -= 8 - bi; ++bi; }
        const int bj = bi + rem;

        // A j-fragments: pj2[mr][ks16] = p[row][bj*32 + ks16*16 + lg2*8 .. +8]
        f16x8 pj2[2][2];
        #pragma unroll
        for (int mr = 0; mr < 2; ++mr)
            #pragma unroll
            for (int k16 = 0; k16 < 2; ++k16)
                pj2[mr][k16] = *(const f16x8*)&P[rowb + mr * 32 + l31][bj * 32 + k16 * 16 + lg2 * 8];

        unsigned voffA = lane_byte + (unsigned)s * SB_BYTES + (unsigned)(ibcS * 65536);
        unsigned voffB = voffA + 4096u;

        // prologue: fill pipeline to depth 2 (clusters 0,1)
        f16x8 B0[4], B1[4], B2[4], B3[4];
        LOADB(B0)
        LOADB(B1)

        // steady ibcs (all but the last of this superblock)
        #pragma unroll 1
        for (int ibc = ibcS; ibc < ibcE - 1; ++ibc) {
            LOAD_PIS(ibc)
            LOADB(B2)  WAITN(8)  MFMA_CLUSTER(B0, 0)
            LOADB(B3)  WAITN(8)  MFMA_CLUSTER(B1, 1)
            LOADB(B0)  WAITN(8)  MFMA_CLUSTER(B2, 2)
            LOADB(B1)  WAITN(8)  MFMA_CLUSTER(B3, 3)
            LOADB(B2)  WAITN(8)  MFMA_CLUSTER(B0, 4)
            LOADB(B3)  WAITN(8)  MFMA_CLUSTER(B1, 5)
            LOADB(B0)  WAITN(8)  MFMA_CLUSTER(B2, 6)
            LOADB(B1)  WAITN(8)  MFMA_CLUSTER(B3, 7)
        }

        // final ibc: steps 0-5 prefetch in-superblock; 6,7 drain down. Every def consumed.
        {
            LOAD_PIS(ibcE - 1)
            LOADB(B2)  WAITN(8)  MFMA_CLUSTER(B0, 0)
            LOADB(B3)  WAITN(8)  MFMA_CLUSTER(B1, 1)
            LOADB(B0)  WAITN(8)  MFMA_CLUSTER(B2, 2)
            LOADB(B1)  WAITN(8)  MFMA_CLUSTER(B3, 3)
            LOADB(B2)  WAITN(8)  MFMA_CLUSTER(B0, 4)
            LOADB(B3)  WAITN(8)  MFMA_CLUSTER(B1, 5)
                       WAITN(4)  MFMA_CLUSTER(B2, 6)
                       WAITN(0)  MFMA_CLUSTER(B3, 7)
        }
    }

    // last split also does the folded W_w matvec tail: A = P directly
    if (ks == KSPLIT - 1) {
        #pragma unroll 1
        for (int jc = 0; jc < 8; ++jc) {
            unsigned vA = TAIL_OFF + (unsigned)(jc * 4) * 2048u + lane_byte;
            f16x8 bfr[4];
            bfr[0] = LDV(vA);           bfr[1] = LDV(vA + 512);
            bfr[2] = LDV(vA + 4096);    bfr[3] = LDV(vA + 4608);
            #pragma unroll
            for (int mr = 0; mr < 2; ++mr) {
                const f16x8 a0 = *(const f16x8*)&P[rowb + mr * 32 + l31][jc * 32 + lg2 * 8];
                const f16x8 a1 = *(const f16x8*)&P[rowb + mr * 32 + l31][jc * 32 + 16 + lg2 * 8];
                acc[mr][0] = __builtin_amdgcn_mfma_f32_32x32x16_f16(a0, bfr[0], acc[mr][0], 0, 0, 0);
                acc[mr][1] = __builtin_amdgcn_mfma_f32_32x32x16_f16(a0, bfr[1], acc[mr][1], 0, 0, 0);
                acc[mr][0] = __builtin_amdgcn_mfma_f32_32x32x16_f16(a1, bfr[2], acc[mr][0], 0, 0, 0);
                acc[mr][1] = __builtin_amdgcn_mfma_f32_32x32x16_f16(a1, bfr[3], acc[mr][1], 0, 0, 0);
            }
        }
    }

    // write fp32 partials; 32x32 C/D: col=lane&31, row=(r&3)+8*(r>>2)+4*lg2
    float* base = part + ((size_t)ks * NB + m0) * DD;
    #pragma unroll
    for (int mr = 0; mr < 2; ++mr)
        #pragma unroll
        for (int nt = 0; nt < 2; ++nt) {
            const int col = coln + nt * 32 + l31;
            #pragma unroll
            for (int r = 0; r < 16; ++r) {
                const int row = rowb + mr * 32 + (r & 3) + 8 * (r >> 2) + 4 * lg2;
                base[(size_t)row * DD + col] = acc[mr][nt][r];
            }
        }
}

// ---------------- epilogue: reduce splits, +W_b, tanh, 5-class logits, log_softmax --------
// 8 threads per batch row (k-split 16 each) + shuffle reduce
__global__ void finish(const float* __restrict__ part, const float* __restrict__ Wb,
                       const float* __restrict__ Wsw, const float* __restrict__ Wsb,
                       float* __restrict__ out) {
    int t  = blockIdx.x * 256 + threadIdx.x;
    int b  = t >> 3;
    int kq = t & 7;                 // k-eighth
    if (b >= NB) return;
    float lg[NCLS];
    #pragma unroll
    for (int c = 0; c < NCLS; ++c) lg[c] = 0.f;

    const float* pb = part + (size_t)b * DD + kq * 16;
    #pragma unroll 1
    for (int k4 = 0; k4 < 4; ++k4) {
        float4 tt = *(const float4*)(Wb + kq * 16 + k4 * 4);
        #pragma unroll
        for (int s = 0; s < KSPLIT; ++s) {
            float4 p = *(const float4*)(pb + (size_t)s * NB * DD + k4 * 4);
            tt.x += p.x; tt.y += p.y; tt.z += p.z; tt.w += p.w;
        }
        float tq[4] = {tt.x, tt.y, tt.z, tt.w};
        #pragma unroll
        for (int q = 0; q < 4; ++q) {
            float h = tanhf(tq[q]);
            int k = kq * 16 + k4 * 4 + q;
            #pragma unroll
            for (int c = 0; c < NCLS; ++c)
                lg[c] += h * Wsw[c * DD + k];
        }
    }
    // reduce across the 8 k-eighth lanes (lane bits 0..2)
    #pragma unroll
    for (int c = 0; c < NCLS; ++c) {
        lg[c] += __shfl_xor(lg[c], 1);
        lg[c] += __shfl_xor(lg[c], 2);
        lg[c] += __shfl_xor(lg[c], 4);
    }
    if (kq == 0) {
        #pragma unroll
        for (int c = 0; c < NCLS; ++c) lg[c] += Wsb[c];
        float mx = lg[0];
        #pragma unroll
        for (int c = 1; c < NCLS; ++c) mx = fmaxf(mx, lg[c]);
        float sum = 0.f;
        #pragma unroll
        for (int c = 0; c < NCLS; ++c) sum += expf(lg[c] - mx);
        float lse = logf(sum);
        #pragma unroll
        for (int c = 0; c < NCLS; ++c) out[b * NCLS + c] = lg[c] - mx - lse;
    }
}

extern "C" void kernel_launch(void* const* d_in, const int* in_sizes, int n_in,
                              void* d_out, int out_size, void* d_ws, size_t ws_size,
                              hipStream_t stream) {
    const float* left  = (const float*)d_in[0];
    const float* right = (const float*)d_in[1];
    const float* V     = (const float*)d_in[2];
    const float* Ww    = (const float*)d_in[3];
    const float* Wb    = (const float*)d_in[4];
    const float* Wsw   = (const float*)d_in[5];
    const float* Wsb   = (const float*)d_in[6];
    float* out = (float*)d_out;

    _Float16* Vt = (_Float16*)d_ws;                       // 9,502,720 B incl. tail
    float* part  = (float*)((char*)d_ws + PART_OFF);      // 33,554,432 B

    hipLaunchKernelGGL(prep_vt, dim3(2320), dim3(256), 0, stream, V, Ww, Vt);
    hipLaunchKernelGGL(gemm_bilinear, dim3((NB / BM) * KSPLIT), dim3(256), 0, stream,
                       left, right, Vt, part);
    hipLaunchKernelGGL(finish, dim3(NB * 8 / 256), dim3(256), 0, stream, part, Wb, Wsw, Wsb, out);
}

// Round 14
// 97.687 us; speedup vs baseline: 1.0729x; 1.0729x over previous
//
#include <hip/hip_runtime.h>
#include <hip/hip_fp16.h>
#include <math.h>

typedef _Float16 f16x8 __attribute__((ext_vector_type(8)));
typedef _Float16 f16x4 __attribute__((ext_vector_type(4)));
typedef float f32x4 __attribute__((ext_vector_type(4)));

#define DD     128     // d
#define D2     256     // 2d
#define NB     8192    // batch
#define NCLS   5
#define KSPLIT 8
#define BM     128
#define PPAD   258     // row stride 516B = 129 dw == 1 mod 32 -> conflict-free
#define NSB    36      // 8x8 block-triangle: 28 off-diag (V+V^T) + 8 diag (raw V)
#define SB_BYTES  262144u              // 128 granules * 128 n * 16 B
#define TAIL_OFF  (36u * 262144u)      // W_w tail after all superblocks
#define PART_OFF  (10u * 1048576u)     // fp32 partials at +10 MB

// ---- prep: build symmetrized Vt fp16 in MFMA fragment layout ----------------------------
__global__ void prep_vt(const float* __restrict__ V, const float* __restrict__ Ww,
                        _Float16* __restrict__ Vt) {
    int t = blockIdx.x * 256 + threadIdx.x;      // thread per (granule-unit, n)
    int u = t >> 7;
    int n = t & 127;
    f16x8 v;
    if (u < NSB * 128) {
        int s = u >> 7, g = u & 127;
        int bi = 0, rem = s;
        while (rem >= 8 - bi) { rem -= 8 - bi; ++bi; }
        int bj = bi + rem;
        int i  = bi * 32 + (g >> 2);
        int j0 = bj * 32 + (g & 3) * 8;
        if (bi == bj) {
            #pragma unroll
            for (int e = 0; e < 8; ++e)
                v[e] = (_Float16)V[((size_t)i * 256 + j0 + e) * 128 + n];
        } else {
            #pragma unroll
            for (int e = 0; e < 8; ++e)
                v[e] = (_Float16)(V[((size_t)i * 256 + j0 + e) * 128 + n]
                                + V[((size_t)(j0 + e) * 256 + i) * 128 + n]);
        }
    } else {
        int g = u - NSB * 128;                   // 0..31
        int j0 = g * 8;
        #pragma unroll
        for (int e = 0; e < 8; ++e)
            v[e] = (_Float16)Ww[n * D2 + j0 + e];
    }
    *(f16x8*)(Vt + (size_t)u * 1024 + n * 8) = v;
}

// ---------------- main: tp_partial[ks][b][k] via outer-product-A MFMA GEMM ----------------
// 2x2 wave grid (mr=4, nr=4). Inline-asm B-loads (pinned issue order, owned counted vmcnt).
// The wait carries the buffer registers as in/out operands: MFMAs can't rise above their
// wait, but the COMPILER is otherwise free to software-pipeline a-gen / pis-reads / other
// buffers' MFMAs across cluster boundaries (no sched_barrier, no setprio fences).
__global__ __launch_bounds__(256, 2) void gemm_bilinear(
        const float* __restrict__ left, const float* __restrict__ right,
        const _Float16* __restrict__ Vt, float* __restrict__ part) {
    __shared__ _Float16 P[BM][PPAD];

    const int bid = blockIdx.x;
    const int ks  = bid & 7;       // == XCD id under round-robin dispatch -> slice per XCD L2
    const int m0  = (bid >> 3) * BM;
    const int tid = threadIdx.x;

    // stage phrase tile (fp32 global -> fp16 LDS), coalesced float4 reads
    for (int it = 0; it < 32; ++it) {
        int f4  = it * 256 + tid;          // float4 index over [128][256]
        int row = f4 >> 6;
        int col = (f4 & 63) * 4;
        const float* src = (col < DD) ? (left  + (size_t)(m0 + row) * DD + col)
                                      : (right + (size_t)(m0 + row) * DD + (col - DD));
        float4 x = *(const float4*)src;
        f16x4 hv;
        hv[0] = (_Float16)x.x; hv[1] = (_Float16)x.y;
        hv[2] = (_Float16)x.z; hv[3] = (_Float16)x.w;
        *(f16x4*)&P[row][col] = hv;
    }
    __syncthreads();

    const int lane = tid & 63;
    const int wid  = tid >> 6;
    const int wm   = wid >> 1, wn = wid & 1;   // 2x2 wave grid, 64x64 wave tile
    const int l15  = lane & 15, lg = lane >> 4;
    const int rowb = wm * 64;
    const int coln = wn * 64;

    f32x4 acc[4][4];
    #pragma unroll
    for (int u = 0; u < 4; ++u)
        #pragma unroll
        for (int w = 0; w < 4; ++w)
            acc[u][w] = (f32x4){0.f, 0.f, 0.f, 0.f};

    const unsigned lane_nbyte = (unsigned)((coln + l15) * 16);
    #define LDV(off) (*(const f16x8*)((const char*)Vt + (off)))

    // inline-asm B-load: 4 x dwordx4, saddr form (vdst, voffset, s[base]) + imm offsets.
    #define LOADB(BUF)                                                                    \
        asm volatile("global_load_dwordx4 %0, %4, %5\n\t"                                 \
                     "global_load_dwordx4 %1, %4, %5 offset:256\n\t"                      \
                     "global_load_dwordx4 %2, %4, %5 offset:512\n\t"                      \
                     "global_load_dwordx4 %3, %4, %5 offset:768"                          \
            : "=&v"(BUF[0]), "=&v"(BUF[1]), "=&v"(BUF[2]), "=&v"(BUF[3])                  \
            : "v"(voff), "s"(Vt));                                                        \
        voff += 8192u;

    // counted wait that DEFINES the buffer it guards: consuming MFMAs are data-dependent
    // on this asm, so they can't be scheduled above it; nothing else is fenced.
    #define WAITN(N, BUF)                                                                 \
        asm volatile("s_waitcnt vmcnt(" #N ")"                                            \
            : "+v"(BUF[0]), "+v"(BUF[1]), "+v"(BUF[2]), "+v"(BUF[3]));

    #define MFMA_CLUSTER(BUF, IBE)                                                        \
        _Pragma("unroll")                                                                 \
        for (int mr = 0; mr < 4; ++mr) {                                                  \
            const _Float16 sc = pis[mr][IBE];                                             \
            const f16x8 a = pj[mr] * sc;                                                  \
            _Pragma("unroll")                                                             \
            for (int nr = 0; nr < 4; ++nr)                                                \
                acc[mr][nr] = __builtin_amdgcn_mfma_f32_16x16x32_f16(a, BUF[nr], acc[mr][nr], 0, 0, 0); \
        }

    #define LOAD_PIS(IBC)                                                                 \
        f16x8 pis[4];                                                                     \
        _Pragma("unroll")                                                                 \
        for (int mr = 0; mr < 4; ++mr)                                                    \
            pis[mr] = *(const f16x8*)&P[rowb + mr * 16 + l15][bi * 32 + (IBC) * 8];

    #pragma unroll 1
    for (int si = 0; si < 5; ++si) {
        int s, ibcS, ibcE;
        if (si < 4) { s = ks * 4 + si;      ibcS = 0;            ibcE = 4; }
        else        { s = 32 + (ks >> 1);   ibcS = (ks & 1) * 2; ibcE = ibcS + 2; }

        // decode (bi, bj) from triangle slot (wave-uniform scalar loop)
        int bi = 0, rem = s;
        while (rem >= 8 - bi) { rem -= 8 - bi; ++bi; }
        const int bj = bi + rem;

        // A j-fragments for this superblock (invariant over i)
        f16x8 pj[4];
        #pragma unroll
        for (int mr = 0; mr < 4; ++mr)
            pj[mr] = *(const f16x8*)&P[rowb + mr * 16 + l15][bj * 32 + lg * 8];

        unsigned voff = lane_nbyte + (unsigned)s * SB_BYTES + (unsigned)(lg * 2048)
                      + (unsigned)(ibcS * 65536);

        // prologue: fill pipeline to depth 2 (clusters 0,1). Nothing else in flight here.
        f16x8 B0[4], B1[4], B2[4], B3[4];
        LOADB(B0)
        LOADB(B1)

        // steady ibcs (all but the last of this superblock)
        #pragma unroll 1
        for (int ibc = ibcS; ibc < ibcE - 1; ++ibc) {
            LOAD_PIS(ibc)
            // cluster c: issue loads for c+2 into B[(c+2)%4], wait vmcnt(8), consume B[c%4]
            LOADB(B2)  WAITN(8, B0)  MFMA_CLUSTER(B0, 0)
            LOADB(B3)  WAITN(8, B1)  MFMA_CLUSTER(B1, 1)
            LOADB(B0)  WAITN(8, B2)  MFMA_CLUSTER(B2, 2)
            LOADB(B1)  WAITN(8, B3)  MFMA_CLUSTER(B3, 3)
            LOADB(B2)  WAITN(8, B0)  MFMA_CLUSTER(B0, 4)
            LOADB(B3)  WAITN(8, B1)  MFMA_CLUSTER(B1, 5)
            LOADB(B0)  WAITN(8, B2)  MFMA_CLUSTER(B2, 6)
            LOADB(B1)  WAITN(8, B3)  MFMA_CLUSTER(B3, 7)
        }

        // final ibc: steps 0-5 still prefetch (targets stay inside this superblock);
        // steps 6,7 issue nothing and drain down -> every def consumed, clean exit.
        {
            LOAD_PIS(ibcE - 1)
            LOADB(B2)  WAITN(8, B0)  MFMA_CLUSTER(B0, 0)
            LOADB(B3)  WAITN(8, B1)  MFMA_CLUSTER(B1, 1)
            LOADB(B0)  WAITN(8, B2)  MFMA_CLUSTER(B2, 2)
            LOADB(B1)  WAITN(8, B3)  MFMA_CLUSTER(B3, 3)
            LOADB(B2)  WAITN(8, B0)  MFMA_CLUSTER(B0, 4)
            LOADB(B3)  WAITN(8, B1)  MFMA_CLUSTER(B1, 5)
                       WAITN(4, B2)  MFMA_CLUSTER(B2, 6)
                       WAITN(0, B3)  MFMA_CLUSTER(B3, 7)
        }
    }

    // last split also does the folded W_w matvec tail: A = P directly
    if (ks == KSPLIT - 1) {
        #pragma unroll 1
        for (int jc = 0; jc < 8; ++jc) {
            unsigned voff = TAIL_OFF + (unsigned)((jc * 4 + lg) * 2048) + lane_nbyte;
            f16x8 bfr[4];
            #pragma unroll
            for (int nr = 0; nr < 4; ++nr) bfr[nr] = LDV(voff + nr * 256);
            #pragma unroll
            for (int mr = 0; mr < 4; ++mr) {
                const f16x8 a = *(const f16x8*)&P[rowb + mr * 16 + l15][jc * 32 + lg * 8];
                #pragma unroll
                for (int nr = 0; nr < 4; ++nr)
                    acc[mr][nr] = __builtin_amdgcn_mfma_f32_16x16x32_f16(a, bfr[nr], acc[mr][nr], 0, 0, 0);
            }
        }
    }

    // write fp32 partials; C/D layout: col = lane&15, row = (lane>>4)*4 + q  [m89-verified]
    float* base = part + ((size_t)ks * NB + m0) * DD;
    #pragma unroll
    for (int mr = 0; mr < 4; ++mr)
        #pragma unroll
        for (int nr = 0; nr < 4; ++nr) {
            const int col = coln + nr * 16 + l15;
            #pragma unroll
            for (int q = 0; q < 4; ++q) {
                const int row = rowb + mr * 16 + lg * 4 + q;
                base[(size_t)row * DD + col] = acc[mr][nr][q];
            }
        }
}

// ---------------- epilogue: reduce splits, +W_b, tanh, 5-class logits, log_softmax --------
// 8 threads per batch row (k-split 16 each) + shuffle reduce
__global__ void finish(const float* __restrict__ part, const float* __restrict__ Wb,
                       const float* __restrict__ Wsw, const float* __restrict__ Wsb,
                       float* __restrict__ out) {
    int t  = blockIdx.x * 256 + threadIdx.x;
    int b  = t >> 3;
    int kq = t & 7;                 // k-eighth
    if (b >= NB) return;
    float lg[NCLS];
    #pragma unroll
    for (int c = 0; c < NCLS; ++c) lg[c] = 0.f;

    const float* pb = part + (size_t)b * DD + kq * 16;
    #pragma unroll 1
    for (int k4 = 0; k4 < 4; ++k4) {
        float4 tt = *(const float4*)(Wb + kq * 16 + k4 * 4);
        #pragma unroll
        for (int s = 0; s < KSPLIT; ++s) {
            float4 p = *(const float4*)(pb + (size_t)s * NB * DD + k4 * 4);
            tt.x += p.x; tt.y += p.y; tt.z += p.z; tt.w += p.w;
        }
        float tq[4] = {tt.x, tt.y, tt.z, tt.w};
        #pragma unroll
        for (int q = 0; q < 4; ++q) {
            float h = tanhf(tq[q]);
            int k = kq * 16 + k4 * 4 + q;
            #pragma unroll
            for (int c = 0; c < NCLS; ++c)
                lg[c] += h * Wsw[c * DD + k];
        }
    }
    // reduce across the 8 k-eighth lanes (lane bits 0..2)
    #pragma unroll
    for (int c = 0; c < NCLS; ++c) {
        lg[c] += __shfl_xor(lg[c], 1);
        lg[c] += __shfl_xor(lg[c], 2);
        lg[c] += __shfl_xor(lg[c], 4);
    }
    if (kq == 0) {
        #pragma unroll
        for (int c = 0; c < NCLS; ++c) lg[c] += Wsb[c];
        float mx = lg[0];
        #pragma unroll
        for (int c = 1; c < NCLS; ++c) mx = fmaxf(mx, lg[c]);
        float sum = 0.f;
        #pragma unroll
        for (int c = 0; c < NCLS; ++c) sum += expf(lg[c] - mx);
        float lse = logf(sum);
        #pragma unroll
        for (int c = 0; c < NCLS; ++c) out[b * NCLS + c] = lg[c] - mx - lse;
    }
}

extern "C" void kernel_launch(void* const* d_in, const int* in_sizes, int n_in,
                              void* d_out, int out_size, void* d_ws, size_t ws_size,
                              hipStream_t stream) {
    const float* left  = (const float*)d_in[0];
    const float* right = (const float*)d_in[1];
    const float* V     = (const float*)d_in[2];
    const float* Ww    = (const float*)d_in[3];
    const float* Wb    = (const float*)d_in[4];
    const float* Wsw   = (const float*)d_in[5];
    const float* Wsb   = (const float*)d_in[6];
    float* out = (float*)d_out;

    _Float16* Vt = (_Float16*)d_ws;                       // 9,502,720 B incl. tail
    float* part  = (float*)((char*)d_ws + PART_OFF);      // 33,554,432 B

    hipLaunchKernelGGL(prep_vt, dim3(2320), dim3(256), 0, stream, V, Ww, Vt);
    hipLaunchKernelGGL(gemm_bilinear, dim3((NB / BM) * KSPLIT), dim3(256), 0, stream,
                       left, right, Vt, part);
    hipLaunchKernelGGL(finish, dim3(NB * 8 / 256), dim3(256), 0, stream, part, Wb, Wsw, Wsb, out);
}